// Round 10
// baseline (589.462 us; speedup 1.0000x reference)
//
#include <hip/hip_runtime.h>

#define IND    256
#define NTASK  (1024 * 2048)   // (batch, pair) tasks

__global__ void FeatureEncodingLayer_30374008718005_kernel(
        const float* __restrict__ X,      // [1024][256]
        const float* __restrict__ W,      // [4096][256]
        const float* __restrict__ bias,   // [4096]
        float* __restrict__ outf)         // [1024][4][4][2048] float32 = Re(kron)
{
    const int stride = gridDim.x * blockDim.x;
    for (int t = blockIdx.x * blockDim.x + threadIdx.x; t < NTASK; t += stride) {
        const int b = t >> 11;            // 2048 pairs per batch row
        const int p = t & 2047;

        const float4* xr = reinterpret_cast<const float4*>(X + (size_t)b * IND);
        const float4* wa = reinterpret_cast<const float4*>(W + (size_t)(2 * p) * IND);
        const float4* wb = reinterpret_cast<const float4*>(W + (size_t)(2 * p + 1) * IND);

        float dA = 0.f, dB = 0.f;
#pragma unroll 8
        for (int q = 0; q < IND / 4; ++q) {
            const float4 xv = xr[q];
            const float4 av = wa[q];
            const float4 bv = wb[q];
            dA = fmaf(xv.x, av.x, dA); dA = fmaf(xv.y, av.y, dA);
            dA = fmaf(xv.z, av.z, dA); dA = fmaf(xv.w, av.w, dA);
            dB = fmaf(xv.x, bv.x, dB); dB = fmaf(xv.y, bv.y, dB);
            dB = fmaf(xv.z, bv.z, dB); dB = fmaf(xv.w, bv.w, dB);
        }
        const float tA = dA + bias[2 * p];
        const float tB = dB + bias[2 * p + 1];

        float sA, cA, sB, cB;
        sincosf(tA, &sA, &cA);
        sincosf(tB, &sB, &cB);
        const float ca = 0.5f * (1.f + cA);   // cos^2(tA/2)
        const float sa = 0.5f * (1.f - cA);   // sin^2(tA/2)
        const float oa = 0.5f * sA;           // sin(tA)/2
        const float cb = 0.5f * (1.f + cB);
        const float sb = 0.5f * (1.f - cB);
        const float ob = 0.5f * sB;
        const float oo = oa * ob;

        // Re(kron[b,p,r,c]), rc = 4r+c; kron = Ra ⊗ Rb, r=2iA+iB, c=2jA+jB.
        // Ra = [[ca, i·oa], [-i·oa, sa]] (A-unit), same for B with cb/ob/sb.
        float re[16];
        re[ 0] =  ca * cb;  re[ 1] = 0.f;      re[ 2] = 0.f;      re[ 3] = -oo;
        re[ 4] = 0.f;       re[ 5] =  ca * sb; re[ 6] =  oo;      re[ 7] = 0.f;
        re[ 8] = 0.f;       re[ 9] =  oo;      re[10] =  sa * cb; re[11] = 0.f;
        re[12] = -oo;       re[13] = 0.f;      re[14] = 0.f;      re[15] =  sa * sb;

        // float index = ((b*16 + rc) * 2048) + p
        const size_t base = (size_t)b * 32768 + p;
#pragma unroll
        for (int rc = 0; rc < 16; ++rc)
            outf[base + (size_t)rc * 2048] = re[rc];
    }
}

extern "C" void kernel_launch(void* const* d_in, const int* in_sizes, int n_in,
                              void* d_out, int out_size, void* d_ws, size_t ws_size,
                              hipStream_t stream) {
    const float* X  = (const float*)d_in[0];
    const float* W  = (const float*)d_in[1];
    const float* bv = (const float*)d_in[2];

    FeatureEncodingLayer_30374008718005_kernel<<<dim3(2048), dim3(256), 0, stream>>>(
        X, W, bv, (float*)d_out);
}

// Round 11
// 50.265 us; speedup vs baseline: 11.7272x; 11.7272x over previous
//
#include <hip/hip_runtime.h>

#define IND   256
#define KC    32
#define WGRP  12
#define WROW  (16 * WGRP)   // 192 floats per k-row

__global__ __launch_bounds__(256, 2)
void FeatureEncodingLayer_30374008718005_kernel(
        const float* __restrict__ X,      // [1024][256]
        const float* __restrict__ W,      // [4096][256]
        const float* __restrict__ bias,   // [4096]
        float* __restrict__ outf)         // [1024][4][4][2048] float32 = Re(kron)
{
    __shared__ float Xs[KC][64];    // k-major: Xs[k][b_local], XOR-swizzled cols
    __shared__ float Ws[KC][WROW];  // k-major, units grouped by 8 at stride 12, swizzled

    const int tid = threadIdx.x;
    const int tx  = tid & 15;    // owns pairs 4*tx .. 4*tx+3 (units 8tx..8tx+7)
    const int ty  = tid >> 4;    // owns batches 4*ty .. 4*ty+3

    // staging roles
    const int kq  = tid & 7;     // float4 column within 32-k chunk
    const int rr  = tid >> 3;    // 0..31
    const int vsw = kq << 2;     // write-side swizzle; read side uses ((k>>2)&7)<<2

    const int pt = blockIdx.x & 31;   // pair tile
    const int bt = blockIdx.x >> 5;   // batch tile

    const int b0 = bt * 64;
    const int p0 = pt * 64;
    const int u0 = p0 * 2;

    float acc[4][8];
#pragma unroll
    for (int i = 0; i < 4; ++i)
#pragma unroll
        for (int j = 0; j < 8; ++j) acc[i][j] = 0.f;

    for (int c = 0; c < IND / KC; ++c) {
        if (c) __syncthreads();   // protect previous chunk's reads before overwrite
        // ---- stage X chunk: 64 rows x 32 k, 2 float4 per thread (coalesced) ----
#pragma unroll
        for (int j = 0; j < 2; ++j) {
            const int r = rr + 32 * j;                     // b_local 0..63
            const float4 v = *reinterpret_cast<const float4*>(
                X + (size_t)(b0 + r) * IND + c * KC + kq * 4);
            const int col = r ^ vsw;
            Xs[kq * 4 + 0][col] = v.x;
            Xs[kq * 4 + 1][col] = v.y;
            Xs[kq * 4 + 2][col] = v.z;
            Xs[kq * 4 + 3][col] = v.w;
        }
        // ---- stage W chunk: 128 rows x 32 k, 4 float4 per thread (coalesced) ----
#pragma unroll
        for (int j = 0; j < 4; ++j) {
            const int u = rr + 32 * j;                     // u_local 0..127
            const float4 v = *reinterpret_cast<const float4*>(
                W + (size_t)(u0 + u) * IND + c * KC + kq * 4);
            const int col = ((u >> 3) * WGRP + (u & 7)) ^ vsw;
            Ws[kq * 4 + 0][col] = v.x;
            Ws[kq * 4 + 1][col] = v.y;
            Ws[kq * 4 + 2][col] = v.z;
            Ws[kq * 4 + 3][col] = v.w;
        }
        __syncthreads();
        // ---- compute: 3x ds_read_b128 + 32 FMA per k ----
#pragma unroll 8
        for (int k = 0; k < KC; ++k) {
            const int vr = ((k >> 2) & 7) << 2;
            const float4 xv = *reinterpret_cast<const float4*>(&Xs[k][(ty * 4) ^ vr]);
            const float4 wa = *reinterpret_cast<const float4*>(&Ws[k][(tx * WGRP) ^ vr]);
            const float4 wb = *reinterpret_cast<const float4*>(&Ws[k][(tx * WGRP + 4) ^ vr]);
            const float xr[4] = {xv.x, xv.y, xv.z, xv.w};
            const float wv[8] = {wa.x, wa.y, wa.z, wa.w, wb.x, wb.y, wb.z, wb.w};
#pragma unroll
            for (int rb = 0; rb < 4; ++rb)
#pragma unroll
                for (int i = 0; i < 8; ++i)
                    acc[rb][i] = fmaf(xr[rb], wv[i], acc[rb][i]);
        }
    }

    // ---- epilogue: bias + trig + Re(Ra x Rb) + coalesced float4 stores ----
    const float4 bva = *reinterpret_cast<const float4*>(bias + u0 + tx * 8);
    const float4 bvb = *reinterpret_cast<const float4*>(bias + u0 + tx * 8 + 4);
    const float bv[8] = {bva.x, bva.y, bva.z, bva.w, bvb.x, bvb.y, bvb.z, bvb.w};

#pragma unroll
    for (int rb = 0; rb < 4; ++rb) {
        const int b = b0 + ty * 4 + rb;
        float ca[4], sa[4], cb[4], sb[4], oo[4];
#pragma unroll
        for (int rp = 0; rp < 4; ++rp) {
            const float tA = acc[rb][2 * rp]     + bv[2 * rp];
            const float tB = acc[rb][2 * rp + 1] + bv[2 * rp + 1];
            float sA, cA, sB, cB;
            sincosf(tA, &sA, &cA);
            sincosf(tB, &sB, &cB);
            ca[rp] = 0.5f * (1.f + cA);            // cos^2(tA/2)
            sa[rp] = 0.5f * (1.f - cA);            // sin^2(tA/2)
            cb[rp] = 0.5f * (1.f + cB);
            sb[rp] = 0.5f * (1.f - cB);
            oo[rp] = 0.25f * sA * sB;              // sin(tA)/2 * sin(tB)/2
        }
        // float index = (b*16 + rc)*2048 + p0 + 4*tx
        float* bp = outf + (size_t)b * 32768 + p0 + tx * 4;

#define STORE4(rc, EXPR) do {                                   \
        float4 v_;                                              \
        { const int rp = 0; v_.x = (EXPR); }                    \
        { const int rp = 1; v_.y = (EXPR); }                    \
        { const int rp = 2; v_.z = (EXPR); }                    \
        { const int rp = 3; v_.w = (EXPR); }                    \
        *reinterpret_cast<float4*>(bp + (rc) * 2048) = v_;      \
    } while (0)

        STORE4(0,  ca[rp] * cb[rp]);
        STORE4(1,  0.f);
        STORE4(2,  0.f);
        STORE4(3,  -oo[rp]);
        STORE4(4,  0.f);
        STORE4(5,  ca[rp] * sb[rp]);
        STORE4(6,  oo[rp]);
        STORE4(7,  0.f);
        STORE4(8,  0.f);
        STORE4(9,  oo[rp]);
        STORE4(10, sa[rp] * cb[rp]);
        STORE4(11, 0.f);
        STORE4(12, -oo[rp]);
        STORE4(13, 0.f);
        STORE4(14, 0.f);
        STORE4(15, sa[rp] * sb[rp]);
#undef STORE4
    }
}

extern "C" void kernel_launch(void* const* d_in, const int* in_sizes, int n_in,
                              void* d_out, int out_size, void* d_ws, size_t ws_size,
                              hipStream_t stream) {
    const float* X  = (const float*)d_in[0];
    const float* W  = (const float*)d_in[1];
    const float* bv = (const float*)d_in[2];

    FeatureEncodingLayer_30374008718005_kernel<<<dim3(512), dim3(256), 0, stream>>>(
        X, W, bv, (float*)d_out);
}